// Round 3
// baseline (475.787 us; speedup 1.0000x reference)
//
#include <hip/hip_runtime.h>
#include <hip/hip_bf16.h>
#include <cstdint>
#include <cstddef>

// ---------------------------------------------------------------------------
// DatastoreReaderLayer: S=256 B=4 D=512 N=32768, TEMP=0.5
//   Wqk = Wq^T @ Wk  (512x512, fused-weight trick: project q, not datastore)
//   Q2  = (qb @ Wqk + bq@Wk) * 2s   (s = D^-0.5), bf16
//   cq  = 2s*(qb.(bk@Wq)) + 2s*(bq.bk)
//   E[q,n] = exp(Q2[q,:].k_raw[n,:] + cq[q]);  racc = E@V, l = rowsum(E)
//   attn = (racc/l) @ Wv^T + bv
//   sdot = relu([attn|prev]@Wg1^T + bg1).wg2 ; out = attn*sg + prev*(1-sg)
// ---------------------------------------------------------------------------

typedef unsigned short u16;
typedef u16    u16x8 __attribute__((ext_vector_type(8)));
typedef u16    u16x4 __attribute__((ext_vector_type(4)));
typedef __bf16 bf16x8 __attribute__((ext_vector_type(8)));
typedef float  f32x4 __attribute__((ext_vector_type(4)));

#define MFMA16(a, b, c) __builtin_amdgcn_mfma_f32_16x16x32_bf16( \
    __builtin_bit_cast(bf16x8, (a)), __builtin_bit_cast(bf16x8, (b)), (c), 0, 0, 0)

#define AS1 __attribute__((address_space(1)))
#define AS3 __attribute__((address_space(3)))

__device__ __forceinline__ u16 f2bf(float f) {  // RNE float->bf16
  unsigned u = __builtin_bit_cast(unsigned, f);
  u += 0x7fffu + ((u >> 16) & 1u);
  return (u16)(u >> 16);
}

// async global->LDS, 16B per lane: LDS dest = uniform base + lane*16
__device__ __forceinline__ void dma16(const u16* g, u16* l) {
  __builtin_amdgcn_global_load_lds((const AS1 unsigned int*)g,
                                   (AS3 unsigned int*)l, 16, 0, 0);
}

// ------------------- prep_all: kbf cvt + vt transpose + zeros + vecs --------
__global__ __launch_bounds__(256) void prep_all(
    const float* __restrict__ dk, const float* __restrict__ dv,
    const float* __restrict__ Wq, const float* __restrict__ Wk,
    const float* __restrict__ bk, const float* __restrict__ bq,
    u16* __restrict__ kbf, u16* __restrict__ vt, float* __restrict__ zbase,
    float* __restrict__ cqvec, float* __restrict__ b2pre,
    float* __restrict__ cq0) {
  const int bx = blockIdx.x, t = threadIdx.x;
  if (bx < 4096) {  // dstore_v -> bf16 transposed [512][32768]
    __shared__ u16 Lt[64 * 72];
    const int n0 = (bx & 511) * 64, d0 = (bx >> 9) * 64;
    const int n = t >> 2, c4 = t & 3;
#pragma unroll
    for (int i = 0; i < 4; i++) {
      int col = (c4 + 4 * i) * 4;
      float4 x = *(const float4*)(dv + (size_t)(n0 + n) * 512 + d0 + col);
      Lt[(col + 0) * 72 + n] = f2bf(x.x);
      Lt[(col + 1) * 72 + n] = f2bf(x.y);
      Lt[(col + 2) * 72 + n] = f2bf(x.z);
      Lt[(col + 3) * 72 + n] = f2bf(x.w);
    }
    __syncthreads();
#pragma unroll
    for (int u = 0; u < 2; u++) {
      int unit = t + 256 * u;
      int d = unit >> 3, un = unit & 7;
      *(u16x8*)(vt + (size_t)(d0 + d) * 32768 + n0 + un * 8) =
          *(const u16x8*)&Lt[d * 72 + un * 8];
    }
  } else if (bx < 8192) {  // dstore_k -> bf16 + zero racc/lacc/sdot
    const int j = bx - 4096;
    size_t i0 = ((size_t)j * 256 + t) * 16;
#pragma unroll
    for (int u = 0; u < 4; u++) {
      float4 v = *(const float4*)(dk + i0 + u * 4);
      u16x4 o = {f2bf(v.x), f2bf(v.y), f2bf(v.z), f2bf(v.w)};
      *(u16x4*)(kbf + i0 + u * 4) = o;
    }
    int zi = j * 256 + t;
    if (zi < 131584) ((float4*)zbase)[zi] = make_float4(0.f, 0.f, 0.f, 0.f);
  } else if (bx < 8194) {  // cqvec = bk@Wq, b2pre = bq@Wk
    int e = (bx - 8192) * 256 + t;
    float s1 = 0.f, s2 = 0.f;
    for (int d = 0; d < 512; d++) {
      s1 += bk[d] * Wq[d * 512 + e];
      s2 += bq[d] * Wk[d * 512 + e];
    }
    cqvec[e] = s1;
    b2pre[e] = s2;
  } else {  // cq0 = 2s*(bq.bk)
    __shared__ float red[4];
    float s = 0.f;
    for (int d = t; d < 512; d += 256) s += bq[d] * bk[d];
#pragma unroll
    for (int off = 32; off; off >>= 1) s += __shfl_down(s, off, 64);
    if ((t & 63) == 0) red[t >> 6] = s;
    __syncthreads();
    if (t == 0) cq0[0] = 0.0883883476483184f * (red[0] + red[1] + red[2] + red[3]);
  }
}

// --------------- MFMA GEMM, 64x64 tiles, pipelined staging ------------------
// TRANSA: C = A^T@B, A [KK,512] (k-rows); else A [M,KK] rows (CONCAT splits).
// TRANSB: B [N,KK] rows; else B [KK,512].
// CQ (bx==0): cqout[r] = alpha*(A[r,:].bkv) + cq0buf[0]
// GATE: sdot[r] += sum_col relu((acc+bias)*alpha)*wg2[col]  (no C store)
template <bool TRANSA, bool TRANSB, bool CONCAT, bool RELU, bool OUTBF16,
          bool ROWSCALE, bool CQ, bool GATE, int KK>
__global__ __launch_bounds__(256, 2) void gemm64(
    const float* __restrict__ A, const float* __restrict__ A2,
    const float* __restrict__ B, const float* __restrict__ bias,
    const float* __restrict__ lvec, const float* __restrict__ bkv,
    const float* __restrict__ wg2, float alpha, void* __restrict__ Cv,
    float* __restrict__ cqout, const float* __restrict__ cq0buf,
    float* __restrict__ sdot) {
  __shared__ u16 As[64 * 72];
  __shared__ u16 Bs[64 * 72];
  const int tid = threadIdx.x;
  const int w = tid >> 6, lane = tid & 63, quad = lane >> 4, l15 = lane & 15;
  const int m0 = blockIdx.y * 64, n0 = blockIdx.x * 64;
  const int arow = tid >> 2, ac4 = tid & 3;
  float rs = 1.0f;
  if (ROWSCALE) rs = 1.0f / lvec[m0 + arow];
  const bool docq = CQ && (blockIdx.x == 0);
  float cqacc = 0.f;
  const f32x4 fzero = {0.f, 0.f, 0.f, 0.f};
  f32x4 acc[4];
#pragma unroll
  for (int i = 0; i < 4; i++) acc[i] = fzero;

  float4 ra[4], rb[4], rk[4];
  auto loadA = [&](int k0) {
    const float* src;
    if (TRANSA)
      src = A + (size_t)(k0 + arow) * 512 + m0;
    else if (CONCAT)
      src = (k0 < 512) ? (A + (size_t)(m0 + arow) * 512 + k0)
                       : (A2 + (size_t)(m0 + arow) * 512 + (k0 - 512));
    else
      src = A + (size_t)(m0 + arow) * KK + k0;
#pragma unroll
    for (int i = 0; i < 4; i++) ra[i] = *(const float4*)(src + (ac4 + 4 * i) * 4);
  };
  auto loadB = [&](int k0) {
    const float* src = TRANSB ? (B + (size_t)(n0 + arow) * KK + k0)
                              : (B + (size_t)(k0 + arow) * 512 + n0);
#pragma unroll
    for (int i = 0; i < 4; i++) rb[i] = *(const float4*)(src + (ac4 + 4 * i) * 4);
  };
  auto loadK = [&](int k0) {
#pragma unroll
    for (int i = 0; i < 4; i++) rk[i] = *(const float4*)(bkv + k0 + (ac4 + 4 * i) * 4);
  };

  loadA(0);
  loadB(0);
  if (docq) loadK(0);
#pragma unroll
  for (int k0 = 0; k0 < KK; k0 += 64) {
    __syncthreads();
#pragma unroll
    for (int i = 0; i < 4; i++) {
      int col = (ac4 + 4 * i) * 4;
      float4 x = ra[i];
      if (ROWSCALE) { x.x *= rs; x.y *= rs; x.z *= rs; x.w *= rs; }
      if (TRANSA) {
        As[(col + 0) * 72 + arow] = f2bf(x.x);
        As[(col + 1) * 72 + arow] = f2bf(x.y);
        As[(col + 2) * 72 + arow] = f2bf(x.z);
        As[(col + 3) * 72 + arow] = f2bf(x.w);
      } else {
        u16x4 oa = {f2bf(x.x), f2bf(x.y), f2bf(x.z), f2bf(x.w)};
        *(u16x4*)&As[arow * 72 + col] = oa;
      }
      float4 y = rb[i];
      if (TRANSB) {
        u16x4 ob = {f2bf(y.x), f2bf(y.y), f2bf(y.z), f2bf(y.w)};
        *(u16x4*)&Bs[arow * 72 + col] = ob;
      } else {
        Bs[(col + 0) * 72 + arow] = f2bf(y.x);
        Bs[(col + 1) * 72 + arow] = f2bf(y.y);
        Bs[(col + 2) * 72 + arow] = f2bf(y.z);
        Bs[(col + 3) * 72 + arow] = f2bf(y.w);
      }
      if (docq)
        cqacc += ra[i].x * rk[i].x + ra[i].y * rk[i].y + ra[i].z * rk[i].z +
                 ra[i].w * rk[i].w;
    }
    if (k0 + 64 < KK) {
      loadA(k0 + 64);
      loadB(k0 + 64);
      if (docq) loadK(k0 + 64);
    }
    __syncthreads();
#pragma unroll
    for (int ks = 0; ks < 2; ks++) {
      u16x8 af = *(const u16x8*)&As[(w * 16 + l15) * 72 + ks * 32 + quad * 8];
#pragma unroll
      for (int nt = 0; nt < 4; nt++) {
        u16x8 bf = *(const u16x8*)&Bs[(nt * 16 + l15) * 72 + ks * 32 + quad * 8];
        acc[nt] = MFMA16(af, bf, acc[nt]);
      }
    }
  }

  if (docq) {
    cqacc += __shfl_xor(cqacc, 1, 64);
    cqacc += __shfl_xor(cqacc, 2, 64);
    if (ac4 == 0) cqout[m0 + arow] = alpha * cqacc + cq0buf[0];
  }
  if (GATE) {
    float part[4] = {0.f, 0.f, 0.f, 0.f};
#pragma unroll
    for (int nt = 0; nt < 4; nt++) {
      int col = n0 + nt * 16 + l15;
      float b = bias[col], wv = wg2[col];
#pragma unroll
      for (int i = 0; i < 4; i++) part[i] += fmaxf((acc[nt][i] + b) * alpha, 0.f) * wv;
    }
#pragma unroll
    for (int i = 0; i < 4; i++) {
      float v = part[i];
      v += __shfl_xor(v, 1, 64); v += __shfl_xor(v, 2, 64);
      v += __shfl_xor(v, 4, 64); v += __shfl_xor(v, 8, 64);
      if (l15 == 0) atomicAdd(&sdot[m0 + w * 16 + quad * 4 + i], v);
    }
  } else {
#pragma unroll
    for (int nt = 0; nt < 4; nt++) {
      int col = n0 + nt * 16 + l15;
      float b = bias ? bias[col] : 0.f;
#pragma unroll
      for (int i = 0; i < 4; i++) {
        int row = m0 + w * 16 + quad * 4 + i;
        float y = (acc[nt][i] + b) * alpha;
        if (RELU) y = fmaxf(y, 0.f);
        if (OUTBF16)
          ((u16*)Cv)[(size_t)row * 512 + col] = f2bf(y);
        else
          ((float*)Cv)[(size_t)row * 512 + col] = y;
      }
    }
  }
}

// ------------------------------- flash kernel -------------------------------
// grid 256: xcd=bx&7, qt=(bx>>3)&15, half=bx>>7; rows=(xcd*2+half)*2048,
// 32 subtiles x 64 n. 8 waves: qh=w&1 (2 q-stripes in regs as B-frags),
// nq=w>>1 (16-n quarter). K: A-frags from LDS (global_load_lds dbuf, 1 read
// feeds 2 MFMAs). Logits D is n-contiguous per lane -> b64 Es writes.
// ONE barrier per subtile (Es dbuf + Ks dbuf make phases hazard-free).
__global__ __launch_bounds__(512, 2) void flash(
    const u16* __restrict__ kbf,  // [32768][512] bf16
    const u16* __restrict__ vt,   // [512][32768] bf16
    const u16* __restrict__ q2,   // [1024][512] bf16
    const float* __restrict__ cq, // [1024]
    float* __restrict__ racc,     // [1024][512] fp32, pre-zeroed
    float* __restrict__ lacc) {   // [1024] fp32, pre-zeroed
  __shared__ u16 Ks[2][64 * 520];  // 133,120 B (row pad 8 u16: conflict-free)
  __shared__ u16 Es[2][64 * 72];   //  18,432 B
  const int tid = threadIdx.x;
  const int w = tid >> 6, lane = tid & 63, quad = lane >> 4, l15 = lane & 15;
  const int bx = blockIdx.x;
  const int xcd = bx & 7, idx = bx >> 3;
  const int qt = idx & 15, half = idx >> 4;
  const int rowbase = (xcd * 2 + half) * 2048;
  const int qbase = qt * 64;
  const int qh = w & 1, nq = w >> 1;
  const int colb = w * 64;

  // Q2 as B-fragments: 2 stripes x 16 ksteps = 128 VGPRs
  u16x8 qf[2][16];
  float cqs[2];
#pragma unroll
  for (int st = 0; st < 2; st++) {
    const u16* qp = q2 + (size_t)(qbase + qh * 32 + st * 16 + l15) * 512 + quad * 8;
#pragma unroll
    for (int ks = 0; ks < 16; ks++) qf[st][ks] = *(const u16x8*)(qp + ks * 32);
    cqs[st] = cq[qbase + qh * 32 + st * 16 + l15];
  }
  const f32x4 fzero = {0.f, 0.f, 0.f, 0.f};
  f32x4 acc[4][4];
#pragma unroll
  for (int a = 0; a < 4; a++)
#pragma unroll
    for (int b = 0; b < 4; b++) acc[a][b] = fzero;
  float lp[2] = {0.f, 0.f};

  // each wave DMAs 8 rows of the 64-row subtile, one row per instr
  auto dma_sub = [&](int sub) {
    u16* dst = &Ks[sub & 1][(w * 8) * 520];
    const u16* g = kbf + (size_t)(rowbase + sub * 64 + w * 8) * 512 + lane * 8;
#pragma unroll
    for (int j = 0; j < 8; j++) dma16(g + (size_t)j * 512, dst + j * 520);
  };

  dma_sub(0);
  __builtin_amdgcn_s_waitcnt(0);
  __syncthreads();

#pragma unroll 1
  for (int sub = 0; sub < 32; ++sub) {
    const int buf = sub & 1;
    const int n0 = rowbase + sub * 64;
    if (sub + 1 < 32) dma_sub(sub + 1);  // async into Ks[buf^1]
    // V fragments for this subtile (consumed after the barrier)
    u16x8 bvp[2][4];
#pragma unroll
    for (int nk = 0; nk < 2; nk++)
#pragma unroll
      for (int ct = 0; ct < 4; ct++)
        bvp[nk][ct] = *(const u16x8*)(vt + (size_t)(colb + ct * 16 + l15) * 32768 +
                                      n0 + nk * 32 + quad * 8);
    // logits: A = K (LDS), B = Q (regs); one Ks read feeds 2 MFMAs
    f32x4 sa[2][2];
    sa[0][0] = fzero; sa[0][1] = fzero; sa[1][0] = fzero; sa[1][1] = fzero;
#pragma unroll
    for (int ks = 0; ks < 16; ks++) {
      u16x8 af = *(const u16x8*)&Ks[buf][(nq * 16 + l15) * 520 + ks * 32 + quad * 8];
      sa[0][ks & 1] = MFMA16(af, qf[0][ks], sa[0][ks & 1]);
      sa[1][ks & 1] = MFMA16(af, qf[1][ks], sa[1][ks & 1]);
    }
    // exp + Es write: lane holds n = nq*16+quad*4+i, q = qh*32+st*16+l15
#pragma unroll
    for (int st = 0; st < 2; st++) {
      f32x4 sv = sa[st][0] + sa[st][1];
      u16x4 pk;
      float ls = 0.f;
#pragma unroll
      for (int i = 0; i < 4; i++) {
        float e = __expf(sv[i] + cqs[st]);
        ls += e;
        pk[i] = f2bf(e);
      }
      lp[st] += ls;
      *(u16x4*)&Es[buf][(qh * 32 + st * 16 + l15) * 72 + nq * 16 + quad * 4] = pk;
    }
    __builtin_amdgcn_s_waitcnt(0);  // drain DMA(sub+1) + bvp + LDS
    __syncthreads();
    // PV: A = E (LDS), B = V (regs)
#pragma unroll
    for (int nk = 0; nk < 2; nk++) {
      u16x8 ef[4];
#pragma unroll
      for (int q2i = 0; q2i < 4; q2i++)
        ef[q2i] = *(const u16x8*)&Es[buf][(q2i * 16 + l15) * 72 + nk * 32 + quad * 8];
#pragma unroll
      for (int ct = 0; ct < 4; ct++)
#pragma unroll
        for (int q2i = 0; q2i < 4; q2i++)
          acc[q2i][ct] = MFMA16(ef[q2i], bvp[nk][ct], acc[q2i][ct]);
    }
  }
  // combine partials across the 16 N-chunks
#pragma unroll
  for (int q2i = 0; q2i < 4; q2i++)
#pragma unroll
    for (int ct = 0; ct < 4; ct++) {
      int col = colb + ct * 16 + l15;
#pragma unroll
      for (int i = 0; i < 4; i++) {
        int row = qbase + q2i * 16 + quad * 4 + i;
        atomicAdd(&racc[(size_t)row * 512 + col], acc[q2i][ct][i]);
      }
    }
#pragma unroll
  for (int st = 0; st < 2; st++) {
    float v = lp[st];
    v += __shfl_xor(v, 16, 64);
    v += __shfl_xor(v, 32, 64);
    if (quad == 0) atomicAdd(&lacc[qbase + qh * 32 + st * 16 + l15], v);
  }
}

// ----------------------- finalize: sigma gate + mix -------------------------
__global__ __launch_bounds__(128) void finalize(
    const float* __restrict__ sdot, const float* __restrict__ bg2,
    const float* __restrict__ attn, const float* __restrict__ prev,
    float* __restrict__ out) {
  int r = blockIdx.x, t = threadIdx.x;
  float sg = 1.f / (1.f + __expf(-(sdot[r] + bg2[0])));
  float4 a = ((const float4*)(attn + (size_t)r * 512))[t];
  float4 p = ((const float4*)(prev + (size_t)r * 512))[t];
  float4 o = {a.x * sg + p.x * (1.f - sg), a.y * sg + p.y * (1.f - sg),
              a.z * sg + p.z * (1.f - sg), a.w * sg + p.w * (1.f - sg)};
  ((float4*)(out + (size_t)r * 512))[t] = o;
}

// ---------------------------------------------------------------------------
extern "C" void kernel_launch(void* const* d_in, const int* in_sizes, int n_in,
                              void* d_out, int out_size, void* d_ws, size_t ws_size,
                              hipStream_t stream) {
  const float* q    = (const float*)d_in[0];
  const float* prev = (const float*)d_in[1];
  const float* Wq   = (const float*)d_in[2];
  const float* bq   = (const float*)d_in[3];
  const float* Wk   = (const float*)d_in[4];
  const float* bk   = (const float*)d_in[5];
  const float* Wv   = (const float*)d_in[6];
  const float* bv   = (const float*)d_in[7];
  const float* Wg1  = (const float*)d_in[8];
  const float* bg1  = (const float*)d_in[9];
  const float* Wg2  = (const float*)d_in[10];
  const float* bg2  = (const float*)d_in[11];
  const float* dk   = (const float*)d_in[12];
  const float* dv   = (const float*)d_in[13];
  float* out = (float*)d_out;

  char* ws = (char*)d_ws;  // total footprint 74,461,184 B (same as round 1/2)
  u16*   kbf   = (u16*)(ws);                  // 33,554,432
  u16*   vt    = (u16*)(ws + 33554432);       // 33,554,432
  float* racc  = (float*)(ws + 67108864);     // 2 MB
  float* lacc  = (float*)(ws + 69206016);     // 4 KB
  float* sdot  = (float*)(ws + 69210112);     // 4 KB
  float* cqv   = (float*)(ws + 69214208);     // 4 KB
  u16*   q2    = (u16*)(ws + 69218304);       // 1 MB
  float* Wqk   = (float*)(ws + 70266880);     // 1 MB (old q1 slot)
  float* cqvec = (float*)(ws + 71315456);     // 2 KB
  float* b2pre = (float*)(ws + 71317504);     // 2 KB
  float* cq0   = (float*)(ws + 71319552);     // 64 B
  float* attn  = (float*)(ws + 72364032);     // 2 MB

  // 1) preps: kbf/vt conversion, racc/lacc/sdot zero, cq/bias vectors
  prep_all<<<8195, 256, 0, stream>>>(dk, dv, Wq, Wk, bk, bq, kbf, vt, racc,
                                     cqvec, b2pre, cq0);
  // 2) Wqk = Wq^T @ Wk
  gemm64<true, false, false, false, false, false, false, false, 512>
      <<<dim3(8, 8), 256, 0, stream>>>(Wq, nullptr, Wk, nullptr, nullptr,
                                       nullptr, nullptr, 1.0f, Wqk, nullptr,
                                       nullptr, nullptr);
  // 3) Q2 = (qb @ Wqk + bq@Wk)*2s (bf16), fused cq
  gemm64<false, false, false, false, true, false, true, false, 512>
      <<<dim3(8, 16), 256, 0, stream>>>(q, nullptr, Wqk, b2pre, nullptr, cqvec,
                                        nullptr, 0.0883883476483184f, q2, cqv,
                                        cq0, nullptr);
  // 4) flash attention over datastore
  flash<<<256, 512, 0, stream>>>(kbf, vt, q2, cqv, racc, lacc);
  // 5) attn = (racc/l) @ Wv^T + bv
  gemm64<false, true, false, false, false, true, false, false, 512>
      <<<dim3(8, 16), 256, 0, stream>>>(racc, nullptr, Wv, bv, lacc, nullptr,
                                        nullptr, 1.0f, attn, nullptr, nullptr,
                                        nullptr);
  // 6) sdot = relu([attn|prev]@Wg1^T + bg1).wg2
  gemm64<false, true, true, true, false, false, false, true, 1024>
      <<<dim3(8, 16), 256, 0, stream>>>(attn, prev, Wg1, bg1, nullptr, nullptr,
                                        Wg2, 1.0f, nullptr, nullptr, nullptr,
                                        sdot);
  // 7) gate + mix
  finalize<<<1024, 128, 0, stream>>>(sdot, bg2, attn, prev, out);
}